// Round 6
// baseline (81.725 us; speedup 1.0000x reference)
//
#include <hip/hip_runtime.h>

// Problem constants
constexpr int NB  = 1024;
constexpr int NIN = 512;
constexpr int NJ  = 64;
constexpr int NK  = 8;
constexpr int NC  = NJ * NK;          // 512
constexpr int OUTC = NIN + NJ;        // 576
constexpr float EXPN10 = 4.5399929762484854e-05f;
constexpr float FEAT_BASE = 1024.0f * EXPN10;

typedef __bf16 bf16x8 __attribute__((ext_vector_type(8)));
typedef float floatx16 __attribute__((ext_vector_type(16)));

__device__ __forceinline__ unsigned f2bf(float f) {  // RNE fp32->bf16
  unsigned u = __float_as_uint(f);
  u += 0x7FFFu + ((u >> 16) & 1u);
  return u >> 16;
}

// ---------------------------------------------------------------------------
// Kernel 1 (gemm_fused): grid 16x8 = 128 blocks, 4 waves, 34816 B LDS.
// R5 lesson (guide §5, m97): hipcc drains vmcnt(0) at EVERY s_barrier, so a
// z+1 prefetch issued before z's __syncthreads is completed at that barrier —
// the 2-deep pipeline never existed. R6 fix: issue ALL FOUR z-slices' loads
// (32 dwordx4/thread, ~256 payload VGPRs — fine at 1 wave/SIMD, cap 512)
// before anything else, pinned by sched_barrier(0) against sinking. First
// barrier then waits once for one full-BW transfer (~1.5us) instead of 4
// serial cold round-trips; all z-phases run back-to-back from registers.
// Staging/MFMA/epilogue logic byte-identical to R4 (proven correct).
// ---------------------------------------------------------------------------
__global__ __launch_bounds__(256) void gemm_fused(const float* __restrict__ x,
                                                  const float* __restrict__ T,
                                                  float* __restrict__ Mp,
                                                  uint4* __restrict__ Mb,
                                                  float* __restrict__ na,
                                                  float* __restrict__ out) {
  __shared__ __align__(16) ushort smem_u[2 * 64 * 136];   // 34816 B
  ushort* Xs = smem_u;              // [64][136] bf16 : A tile (b rows, 128 k)
  ushort* Ts = smem_u + 64 * 136;   // [64][136] bf16 : B tile (c rows, 128 k)
  float*  Cs = (float*)smem_u;      // [64][68] fp32 epilogue tile (overlay)

  const int tid = threadIdx.x;
  const int b0 = blockIdx.x * 64;
  const int c0 = blockIdx.y * 64;

  const int lane = tid & 63;
  const int w    = tid >> 6;
  const int l31  = lane & 31;
  const int half = lane >> 5;
  const int arow = (w & 1) * 32 + l31;
  const int bcol = (w >> 1) * 32 + l31;

  // B-transpose thread mapping (fixed across z)
  const int pr   = tid >> 4;        // 0..15 : k-pair index within 32-row group
  const int coff = (tid & 15) * 4;  // 0..60 : c-quad offset

  float4 av0[8], bv0[8], av1[8], bv1[8], av2[8], bv2[8], av3[8], bv3[8];

  auto load_slice = [&](int z, float4 (&av)[8], float4 (&bv)[8]) {
#pragma unroll
    for (int t = 0; t < 4; ++t) {
      const int u = t * 256 + tid;
      const int row = u >> 4, seg = u & 15;
      const size_t base = (size_t)(b0 + row) * NIN + z * 128 + seg * 8;
      av[2 * t]     = *(const float4*)&x[base];
      av[2 * t + 1] = *(const float4*)&x[base + 4];
    }
#pragma unroll
    for (int it = 0; it < 4; ++it) {
      const int k0 = it * 32 + pr * 2;               // local k (even), 0..126
      const size_t base = (size_t)(z * 128 + k0) * NC + c0 + coff;
      bv[2 * it]     = *(const float4*)&T[base];      // row k0
      bv[2 * it + 1] = *(const float4*)&T[base + NC]; // row k0+1
    }
  };

  auto stage_slice = [&](const float4 (&av)[8], const float4 (&bv)[8]) {
#pragma unroll
    for (int t = 0; t < 4; ++t) {
      const int u = t * 256 + tid;
      const int row = u >> 4, seg = u & 15;
      uint4 p;
      p.x = f2bf(av[2 * t].x) | (f2bf(av[2 * t].y) << 16);
      p.y = f2bf(av[2 * t].z) | (f2bf(av[2 * t].w) << 16);
      p.z = f2bf(av[2 * t + 1].x) | (f2bf(av[2 * t + 1].y) << 16);
      p.w = f2bf(av[2 * t + 1].z) | (f2bf(av[2 * t + 1].w) << 16);
      *(uint4*)&Xs[row * 136 + seg * 8] = p;
    }
    unsigned* Tw = (unsigned*)Ts;     // dword view, row stride 68
#pragma unroll
    for (int it = 0; it < 4; ++it) {
      const float* lo = &bv[2 * it].x;
      const float* hi = &bv[2 * it + 1].x;
#pragma unroll
      for (int q = 0; q < 4; ++q) {
        const unsigned val = f2bf(lo[q]) | (f2bf(hi[q]) << 16);
        Tw[(coff + q) * 68 + it * 16 + pr] = val;    // Ts[c][k0..k0+1]
      }
    }
  };

  floatx16 acc = {};
  auto mfma_tile = [&]() {
#pragma unroll
    for (int s = 0; s < 8; ++s) {
      const bf16x8 af = *(const bf16x8*)&Xs[arow * 136 + s * 16 + half * 8];
      const bf16x8 bf = *(const bf16x8*)&Ts[bcol * 136 + s * 16 + half * 8];
      acc = __builtin_amdgcn_mfma_f32_32x32x16_bf16(af, bf, acc, 0, 0, 0);
    }
  };

  // ---- issue ALL tile loads first; pin against sinking ----
  load_slice(0, av0, bv0);
  load_slice(1, av1, bv1);
  load_slice(2, av2, bv2);
  load_slice(3, av3, bv3);
  __builtin_amdgcn_sched_barrier(0);

  // ---- out init (independent; runs while tile loads are in flight) ----
  const int bidf = blockIdx.y * 16 + blockIdx.x;   // 0..127
#pragma unroll
  for (int it = 0; it < 5; ++it) {
    const int li = it * 256 + tid;
    if (li < 1152) {                                 // 147456/128 float4 per block
      const int gi = bidf * 1152 + li;
      const int b = gi / (OUTC / 4);                 // /144 -> magic mul
      const int r = gi - b * (OUTC / 4);
      float4 v;
      if (r < NIN / 4) v = ((const float4*)x)[b * (NIN / 4) + r];
      else v = float4{FEAT_BASE, FEAT_BASE, FEAT_BASE, FEAT_BASE};
      ((float4*)out)[gi] = v;
    }
  }

  // ---- z phases, all operands already in registers ----
  stage_slice(av0, bv0);
  __syncthreads();
  mfma_tile();
  __syncthreads();
  stage_slice(av1, bv1);
  __syncthreads();
  mfma_tile();
  __syncthreads();
  stage_slice(av2, bv2);
  __syncthreads();
  mfma_tile();
  __syncthreads();
  stage_slice(av3, bv3);
  __syncthreads();
  mfma_tile();
  __syncthreads();                  // protect LDS before Cs overlay

  // ---- epilogue: acc -> Cs (stride 68, conflict-free), then prep rows ----
#pragma unroll
  for (int reg = 0; reg < 16; ++reg) {
    const int row = (reg & 3) + 8 * (reg >> 2) + 4 * half;
    Cs[((w & 1) * 32 + row) * 68 + (w >> 1) * 32 + l31] = acc[reg];
  }
  __syncthreads();

#pragma unroll
  for (int pass = 0; pass < 2; ++pass) {
    const int jl = (tid >> 6) + pass * 4;   // local j 0..7
    const int b  = tid & 63;                // local b
    const float4 m0 = *(const float4*)&Cs[b * 68 + jl * 8];
    const float4 m1 = *(const float4*)&Cs[b * 68 + jl * 8 + 4];
    const int j_g = blockIdx.y * 8 + jl;
    const int idx = j_g * NB + b0 + b;
    ((float4*)Mp)[idx * 2]     = m0;
    ((float4*)Mp)[idx * 2 + 1] = m1;
    float s = m0.x * m0.x;
    s = fmaf(m0.y, m0.y, s); s = fmaf(m0.z, m0.z, s); s = fmaf(m0.w, m0.w, s);
    s = fmaf(m1.x, m1.x, s); s = fmaf(m1.y, m1.y, s); s = fmaf(m1.z, m1.z, s);
    s = fmaf(m1.w, m1.w, s);
    na[idx] = s;
    uint4 pk;
    pk.x = f2bf(m0.x) | (f2bf(m0.y) << 16);
    pk.y = f2bf(m0.z) | (f2bf(m0.w) << 16);
    pk.z = f2bf(m1.x) | (f2bf(m1.y) << 16);
    pk.w = f2bf(m1.z) | (f2bf(m1.w) << 16);
    Mb[idx] = pk;
  }
}

// ---------------------------------------------------------------------------
// Kernel 2: pairwise. R6 rewrite: ZERO LDS, ZERO barriers. Every (a,b) pair
// test is independent — the old cooperative LDS staging forced all 4 waves
// into a load->barrier lockstep whose cold latency serialized the kernel.
// Now each wave streams its b-tiles (Mb uint4 + na scalar) straight from
// global (L2-hot, 16 independent unrolled iterations -> compiler prefetches;
// 4 blocks/CU TLP hides the rest). Same pair set, same prefilter constants,
// same atomics — numerics identical to the proven version.
// ---------------------------------------------------------------------------
__global__ __launch_bounds__(256) void pairwise_kernel(const uint4* __restrict__ Mb,
                                                       const float* __restrict__ na,
                                                       const float* __restrict__ Mp,
                                                       float* __restrict__ out) {
  const int j    = blockIdx.x;
  const int ag   = blockIdx.y;
  const int bh   = blockIdx.z;
  const int tid  = threadIdx.x;
  const int lane = tid & 63;
  const int w    = tid >> 6;
  const int col  = lane & 31;
  const int h    = lane >> 5;
  const int jb   = j * NB;

  const int bbeg = bh * 512;
  const int a0 = ag * 128 + w * 32;

  uint4 araw = uint4{0u, 0u, 0u, 0u};
  if (lane < 32) araw = Mb[jb + a0 + lane];
  const bf16x8 af = __builtin_bit_cast(bf16x8, araw);

  float c995[16];
#pragma unroll
  for (int reg = 0; reg < 16; ++reg) {
    const int row = (reg & 3) + 8 * (reg >> 2) + 4 * h;
    c995[reg] = 0.995f * na[jb + a0 + row];
  }

  const floatx16 zero = {};
  const uint4 zed = uint4{0u, 0u, 0u, 0u};

#pragma unroll 4
  for (int bt = 0; bt < 16; ++bt) {
    const int bidx = bt * 32 + col;
    const uint4 braw = (lane < 32) ? Mb[jb + bbeg + bidx] : zed;
    const bf16x8 bf = __builtin_bit_cast(bf16x8, braw);
    const float nb_l = na[jb + bbeg + bidx];
    const floatx16 P = __builtin_amdgcn_mfma_f32_32x32x16_bf16(af, bf, zero, 0, 0, 0);
    const float rhs = 100.0f - 0.995f * nb_l;

    float t = fmaf(-2.0f, P[0], c995[0]);
#pragma unroll
    for (int reg = 1; reg < 16; ++reg)
      t = fminf(t, fmaf(-2.0f, P[reg], c995[reg]));

    if (__any(t < rhs)) {   // rare: ~diagonal tiles only
#pragma unroll
      for (int reg = 0; reg < 16; ++reg) {
        if (fmaf(-2.0f, P[reg], c995[reg]) < rhs) {
          const int row = (reg & 3) + 8 * (reg >> 2) + 4 * h;
          const int a = a0 + row;
          const int b = bbeg + bt * 32 + col;
          float corr;
          if (a == b) {
            corr = 1.0f - EXPN10;
          } else {
            const float4 av0 = ((const float4*)Mp)[(jb + a) * 2];
            const float4 av1 = ((const float4*)Mp)[(jb + a) * 2 + 1];
            const float4 bv0 = ((const float4*)Mp)[(jb + b) * 2];
            const float4 bv1 = ((const float4*)Mp)[(jb + b) * 2 + 1];
            float d = av0.x - bv0.x; float sq = d * d;
            d = av0.y - bv0.y; sq = fmaf(d, d, sq);
            d = av0.z - bv0.z; sq = fmaf(d, d, sq);
            d = av0.w - bv0.w; sq = fmaf(d, d, sq);
            d = av1.x - bv1.x; sq = fmaf(d, d, sq);
            d = av1.y - bv1.y; sq = fmaf(d, d, sq);
            d = av1.z - bv1.z; sq = fmaf(d, d, sq);
            d = av1.w - bv1.w; sq = fmaf(d, d, sq);
            const float nrm = sqrtf(sq);
            corr = (nrm < 10.0f) ? (__expf(-nrm) - EXPN10) : 0.0f;
          }
          if (corr != 0.0f) atomicAdd(&out[a * OUTC + NIN + j], corr);
        }
      }
    }
  }
}

// ---------------------------------------------------------------------------
extern "C" void kernel_launch(void* const* d_in, const int* in_sizes, int n_in,
                              void* d_out, int out_size, void* d_ws, size_t ws_size,
                              hipStream_t stream) {
  const float* x = (const float*)d_in[0];
  const float* T = (const float*)d_in[1];
  float* out = (float*)d_out;

  // workspace layout (3.25 MB)
  float* Mp  = (float*)d_ws;                         // [64][1024][8] fp32   2 MB
  float* na  = Mp + (size_t)NJ * NB * NK;            // [64][1024]         256 KB
  uint4* Mb  = (uint4*)(na + (size_t)NJ * NB);       // [64][1024] bf16x8    1 MB

  gemm_fused<<<dim3(16, 8), 256, 0, stream>>>(x, T, Mp, Mb, na, out);
  pairwise_kernel<<<dim3(NJ, 8, 2), 256, 0, stream>>>(Mb, na, Mp, out);
}

// Round 7
// 76.088 us; speedup vs baseline: 1.0741x; 1.0741x over previous
//
#include <hip/hip_runtime.h>

// Problem constants
constexpr int NB  = 1024;
constexpr int NIN = 512;
constexpr int NJ  = 64;
constexpr int NK  = 8;
constexpr int NC  = NJ * NK;          // 512
constexpr int OUTC = NIN + NJ;        // 576
constexpr float EXPN10 = 4.5399929762484854e-05f;
constexpr float FEAT_BASE = 1024.0f * EXPN10;

typedef __bf16 bf16x8 __attribute__((ext_vector_type(8)));
typedef float floatx16 __attribute__((ext_vector_type(16)));

__device__ __forceinline__ unsigned f2bf(float f) {  // RNE fp32->bf16
  unsigned u = __float_as_uint(f);
  u += 0x7FFFu + ((u >> 16) & 1u);
  return u >> 16;
}

// ---------------------------------------------------------------------------
// Kernel 1 (gemm_fused): grid 16x8 = 128 blocks, 4 waves, 34816 B LDS.
// Exact R4 version (proven 16us; R5 pipeline and R6 all-upfront variants
// measured equal — the load chain is NOT the residual bottleneck here).
// Batched two-phase staging per z-slice: 16 independent dwordx4 in flight,
// then convert+LDS-write. Inline fp32->bf16, in-block B transpose, out-init
// folded in.
// ---------------------------------------------------------------------------
__global__ __launch_bounds__(256) void gemm_fused(const float* __restrict__ x,
                                                  const float* __restrict__ T,
                                                  float* __restrict__ Mp,
                                                  uint4* __restrict__ Mb,
                                                  float* __restrict__ na,
                                                  float* __restrict__ out) {
  __shared__ __align__(16) ushort smem_u[2 * 64 * 136];   // 34816 B
  ushort* Xs = smem_u;              // [64][136] bf16 : A tile (b rows, 128 k)
  ushort* Ts = smem_u + 64 * 136;   // [64][136] bf16 : B tile (c rows, 128 k)
  float*  Cs = (float*)smem_u;      // [64][68] fp32 epilogue tile (overlay)

  const int tid = threadIdx.x;
  const int b0 = blockIdx.x * 64;
  const int c0 = blockIdx.y * 64;

  const int lane = tid & 63;
  const int w    = tid >> 6;
  const int l31  = lane & 31;
  const int half = lane >> 5;
  const int arow = (w & 1) * 32 + l31;
  const int bcol = (w >> 1) * 32 + l31;

  // B-transpose thread mapping (fixed across z)
  const int pr   = tid >> 4;        // 0..15 : k-pair index within 32-row group
  const int coff = (tid & 15) * 4;  // 0..60 : c-quad offset

  // ---- out init (independent work; out consumed only by pairwise dispatch)
  const int bidf = blockIdx.y * 16 + blockIdx.x;   // 0..127
#pragma unroll
  for (int it = 0; it < 5; ++it) {
    const int li = it * 256 + tid;
    if (li < 1152) {                                 // 147456/128 float4 per block
      const int gi = bidf * 1152 + li;
      const int b = gi / (OUTC / 4);                 // /144 -> magic mul
      const int r = gi - b * (OUTC / 4);
      float4 v;
      if (r < NIN / 4) v = ((const float4*)x)[b * (NIN / 4) + r];
      else v = float4{FEAT_BASE, FEAT_BASE, FEAT_BASE, FEAT_BASE};
      ((float4*)out)[gi] = v;
    }
  }

  floatx16 acc = {};

  for (int z = 0; z < 4; ++z) {
    // ================= load phase: ALL global loads batched =================
    float4 av[8];
#pragma unroll
    for (int t = 0; t < 4; ++t) {
      const int u = t * 256 + tid;
      const int row = u >> 4, seg = u & 15;
      const size_t base = (size_t)(b0 + row) * NIN + z * 128 + seg * 8;
      av[2 * t]     = *(const float4*)&x[base];
      av[2 * t + 1] = *(const float4*)&x[base + 4];
    }
    float4 bv[8];
#pragma unroll
    for (int it = 0; it < 4; ++it) {
      const int k0 = it * 32 + pr * 2;               // local k (even), 0..126
      const size_t base = (size_t)(z * 128 + k0) * NC + c0 + coff;
      bv[2 * it]     = *(const float4*)&T[base];      // row k0
      bv[2 * it + 1] = *(const float4*)&T[base + NC]; // row k0+1
    }

    // ================= write phase: convert + LDS =================
#pragma unroll
    for (int t = 0; t < 4; ++t) {
      const int u = t * 256 + tid;
      const int row = u >> 4, seg = u & 15;
      uint4 p;
      p.x = f2bf(av[2 * t].x) | (f2bf(av[2 * t].y) << 16);
      p.y = f2bf(av[2 * t].z) | (f2bf(av[2 * t].w) << 16);
      p.z = f2bf(av[2 * t + 1].x) | (f2bf(av[2 * t + 1].y) << 16);
      p.w = f2bf(av[2 * t + 1].z) | (f2bf(av[2 * t + 1].w) << 16);
      *(uint4*)&Xs[row * 136 + seg * 8] = p;
    }
    unsigned* Tw = (unsigned*)Ts;     // dword view, row stride 68
#pragma unroll
    for (int it = 0; it < 4; ++it) {
      const float* lo = &bv[2 * it].x;
      const float* hi = &bv[2 * it + 1].x;
#pragma unroll
      for (int q = 0; q < 4; ++q) {
        const unsigned val = f2bf(lo[q]) | (f2bf(hi[q]) << 16);
        Tw[(coff + q) * 68 + it * 16 + pr] = val;    // Ts[c][k0..k0+1]
      }
    }

    __syncthreads();

    // ---- MFMA: 8 steps of K=16 ----
#pragma unroll
    for (int s = 0; s < 8; ++s) {
      const bf16x8 af = *(const bf16x8*)&Xs[arow * 136 + s * 16 + half * 8];
      const bf16x8 bf = *(const bf16x8*)&Ts[bcol * 136 + s * 16 + half * 8];
      acc = __builtin_amdgcn_mfma_f32_32x32x16_bf16(af, bf, acc, 0, 0, 0);
    }
    __syncthreads();
  }

  // ---- epilogue: acc -> Cs (stride 68, conflict-free), then prep rows ----
#pragma unroll
  for (int reg = 0; reg < 16; ++reg) {
    const int row = (reg & 3) + 8 * (reg >> 2) + 4 * half;
    Cs[((w & 1) * 32 + row) * 68 + (w >> 1) * 32 + l31] = acc[reg];
  }
  __syncthreads();

#pragma unroll
  for (int pass = 0; pass < 2; ++pass) {
    const int jl = (tid >> 6) + pass * 4;   // local j 0..7
    const int b  = tid & 63;                // local b
    const float4 m0 = *(const float4*)&Cs[b * 68 + jl * 8];
    const float4 m1 = *(const float4*)&Cs[b * 68 + jl * 8 + 4];
    const int j_g = blockIdx.y * 8 + jl;
    const int idx = j_g * NB + b0 + b;
    ((float4*)Mp)[idx * 2]     = m0;
    ((float4*)Mp)[idx * 2 + 1] = m1;
    float s = m0.x * m0.x;
    s = fmaf(m0.y, m0.y, s); s = fmaf(m0.z, m0.z, s); s = fmaf(m0.w, m0.w, s);
    s = fmaf(m1.x, m1.x, s); s = fmaf(m1.y, m1.y, s); s = fmaf(m1.z, m1.z, s);
    s = fmaf(m1.w, m1.w, s);
    na[idx] = s;
    uint4 pk;
    pk.x = f2bf(m0.x) | (f2bf(m0.y) << 16);
    pk.y = f2bf(m0.z) | (f2bf(m0.w) << 16);
    pk.z = f2bf(m1.x) | (f2bf(m1.y) << 16);
    pk.w = f2bf(m1.z) | (f2bf(m1.w) << 16);
    Mb[idx] = pk;
  }
}

// ---------------------------------------------------------------------------
// Kernel 2: pairwise — proven LDS-staged structure (R6's barrier-free variant
// regressed 18->~25us: private per-wave b-tile reloads + serial load->MFMA
// chains). R7 parameter change: b-split 2->4 (grid 64x8x4 = 2048 blocks).
// Per-block: stage 256 b-entries in ONE round (~5KB LDS), 8 bt iterations.
// Half the exposed staging chain, 2x block-level TLP; same total MFMA work,
// same pair coverage, same prefilter constants and atomics.
// ---------------------------------------------------------------------------
__global__ __launch_bounds__(256) void pairwise_kernel(const uint4* __restrict__ Mb,
                                                       const float* __restrict__ na,
                                                       const float* __restrict__ Mp,
                                                       float* __restrict__ out) {
  const int j    = blockIdx.x;
  const int ag   = blockIdx.y;
  const int bh   = blockIdx.z;
  const int tid  = threadIdx.x;
  const int lane = tid & 63;
  const int w    = tid >> 6;
  const int col  = lane & 31;
  const int h    = lane >> 5;
  const int jb   = j * NB;

  __shared__ uint4 Mb_s[257];    // [256] = zeros for K-pad lanes
  __shared__ float nb_s[256];
  __shared__ float na_s[128];

  const int bbeg = bh * 256;
  Mb_s[tid] = Mb[jb + bbeg + tid];
  nb_s[tid] = na[jb + bbeg + tid];
  if (tid == 0) Mb_s[256] = uint4{0u, 0u, 0u, 0u};

  const int a0 = ag * 128 + w * 32;
  if (lane < 32) na_s[w * 32 + lane] = na[jb + a0 + lane];

  uint4 araw = uint4{0u, 0u, 0u, 0u};
  if (lane < 32) araw = Mb[jb + a0 + lane];
  const bf16x8 af = __builtin_bit_cast(bf16x8, araw);

  __syncthreads();

  float c995[16];
#pragma unroll
  for (int reg = 0; reg < 16; ++reg) {
    const int row = (reg & 3) + 8 * (reg >> 2) + 4 * h;
    c995[reg] = 0.995f * na_s[w * 32 + row];
  }

  const floatx16 zero = {};

#pragma unroll 2
  for (int bt = 0; bt < 8; ++bt) {
    const int bidx = bt * 32 + col;
    const uint4 braw = Mb_s[lane < 32 ? bidx : 256];
    const bf16x8 bf = __builtin_bit_cast(bf16x8, braw);
    const floatx16 P = __builtin_amdgcn_mfma_f32_32x32x16_bf16(af, bf, zero, 0, 0, 0);
    const float nb_l = nb_s[bidx];
    const float rhs = 100.0f - 0.995f * nb_l;

    float t = fmaf(-2.0f, P[0], c995[0]);
#pragma unroll
    for (int reg = 1; reg < 16; ++reg)
      t = fminf(t, fmaf(-2.0f, P[reg], c995[reg]));

    if (__any(t < rhs)) {   // rare: ~diagonal tiles only
#pragma unroll
      for (int reg = 0; reg < 16; ++reg) {
        if (fmaf(-2.0f, P[reg], c995[reg]) < rhs) {
          const int row = (reg & 3) + 8 * (reg >> 2) + 4 * h;
          const int a = a0 + row;
          const int b = bbeg + bt * 32 + col;
          float corr;
          if (a == b) {
            corr = 1.0f - EXPN10;
          } else {
            const float4 av0 = ((const float4*)Mp)[(jb + a) * 2];
            const float4 av1 = ((const float4*)Mp)[(jb + a) * 2 + 1];
            const float4 bv0 = ((const float4*)Mp)[(jb + b) * 2];
            const float4 bv1 = ((const float4*)Mp)[(jb + b) * 2 + 1];
            float d = av0.x - bv0.x; float sq = d * d;
            d = av0.y - bv0.y; sq = fmaf(d, d, sq);
            d = av0.z - bv0.z; sq = fmaf(d, d, sq);
            d = av0.w - bv0.w; sq = fmaf(d, d, sq);
            d = av1.x - bv1.x; sq = fmaf(d, d, sq);
            d = av1.y - bv1.y; sq = fmaf(d, d, sq);
            d = av1.z - bv1.z; sq = fmaf(d, d, sq);
            d = av1.w - bv1.w; sq = fmaf(d, d, sq);
            const float nrm = sqrtf(sq);
            corr = (nrm < 10.0f) ? (__expf(-nrm) - EXPN10) : 0.0f;
          }
          if (corr != 0.0f) atomicAdd(&out[a * OUTC + NIN + j], corr);
        }
      }
    }
  }
}

// ---------------------------------------------------------------------------
extern "C" void kernel_launch(void* const* d_in, const int* in_sizes, int n_in,
                              void* d_out, int out_size, void* d_ws, size_t ws_size,
                              hipStream_t stream) {
  const float* x = (const float*)d_in[0];
  const float* T = (const float*)d_in[1];
  float* out = (float*)d_out;

  // workspace layout (3.25 MB)
  float* Mp  = (float*)d_ws;                         // [64][1024][8] fp32   2 MB
  float* na  = Mp + (size_t)NJ * NB * NK;            // [64][1024]         256 KB
  uint4* Mb  = (uint4*)(na + (size_t)NJ * NB);       // [64][1024] bf16x8    1 MB

  gemm_fused<<<dim3(16, 8), 256, 0, stream>>>(x, T, Mp, Mb, na, out);
  pairwise_kernel<<<dim3(NJ, 8, 4), 256, 0, stream>>>(Mb, na, Mp, out);
}

// Round 8
// 72.148 us; speedup vs baseline: 1.1327x; 1.0546x over previous
//
#include <hip/hip_runtime.h>

// Problem constants
constexpr int NB  = 1024;
constexpr int NIN = 512;
constexpr int NJ  = 64;
constexpr int NK  = 8;
constexpr int NC  = NJ * NK;          // 512
constexpr int OUTC = NIN + NJ;        // 576
constexpr float EXPN10 = 4.5399929762484854e-05f;
constexpr float FEAT_BASE = 1024.0f * EXPN10;

typedef __bf16 bf16x8 __attribute__((ext_vector_type(8)));
typedef float floatx16 __attribute__((ext_vector_type(16)));

__device__ __forceinline__ unsigned f2bf(float f) {  // RNE fp32->bf16
  unsigned u = __float_as_uint(f);
  u += 0x7FFFu + ((u >> 16) & 1u);
  return u >> 16;
}

// ---------------------------------------------------------------------------
// Kernel 1 (gemm_fused) R8: grid 16x16 = 256 blocks (FULL machine), tile
// 64b x 32c, K-split 2-way across wave pairs. R4/R5/R6 proved the load-issue
// chain is not the bottleneck (three structures, all 16us); the untested axis
// was CU coverage (128 blocks = half idle) and per-block serial phase depth
// (4 staged phases). Now: 2 phases, each staging BOTH K-halves' slices
// (A [2][64][136], B [2][32][136] = 51KB LDS); wave (wr,kh) accumulates a
// 32x32 tile of K-half kh; partials summed via Cs[2][64][36] in the epilogue.
// MFMA total unchanged. Staging/pack/transpose idioms byte-level identical
// to the proven R4 patterns.
// ---------------------------------------------------------------------------
__global__ __launch_bounds__(256) void gemm_fused(const float* __restrict__ x,
                                                  const float* __restrict__ T,
                                                  float* __restrict__ Mp,
                                                  uint4* __restrict__ Mb,
                                                  float* __restrict__ na,
                                                  float* __restrict__ out) {
  __shared__ __align__(16) ushort smem_u[2 * 64 * 136 + 2 * 32 * 136];  // 52224 B
  ushort* Xs = smem_u;                     // [2][64][136] bf16 A halves
  ushort* Ts = smem_u + 2 * 64 * 136;      // [2][32][136] bf16 B halves (transposed)
  float*  Cs = (float*)smem_u;             // [2][64][36] fp32 partial tiles (overlay)

  const int tid = threadIdx.x;
  const int b0 = blockIdx.x * 64;
  const int c0 = blockIdx.y * 32;

  const int lane = tid & 63;
  const int w    = tid >> 6;
  const int l31  = lane & 31;
  const int half = lane >> 5;
  const int wr   = w & 1;        // arow half
  const int kh   = w >> 1;       // K half owned by this wave
  const int arow = wr * 32 + l31;

  // B-transpose thread mapping
  const int bk = tid >> 3;        // 0..31 : k-pair index within 64-row group
  const int bc = (tid & 7) * 4;   // 0..28 : c-quad offset

  // ---- out init (256 blocks x 576 float4) ----
  const int bidf = blockIdx.y * 16 + blockIdx.x;   // 0..255
#pragma unroll
  for (int it = 0; it < 3; ++it) {
    const int li = it * 256 + tid;
    if (li < 576) {
      const int gi = bidf * 576 + li;
      const int b = gi / (OUTC / 4);                 // /144 -> magic mul
      const int r = gi - b * (OUTC / 4);
      float4 v;
      if (r < NIN / 4) v = ((const float4*)x)[b * (NIN / 4) + r];
      else v = float4{FEAT_BASE, FEAT_BASE, FEAT_BASE, FEAT_BASE};
      ((float4*)out)[gi] = v;
    }
  }

  floatx16 acc = {};

  for (int z = 0; z < 2; ++z) {
    // ======== load phase: ALL global loads for BOTH K-halves batched ========
    float4 av[16];
#pragma unroll
    for (int kk = 0; kk < 2; ++kk) {
#pragma unroll
      for (int t = 0; t < 4; ++t) {
        const int u = t * 256 + tid;
        const int row = u >> 4, seg = u & 15;
        const size_t base = (size_t)(b0 + row) * NIN + (kk * 2 + z) * 128 + seg * 8;
        av[kk * 8 + 2 * t]     = *(const float4*)&x[base];
        av[kk * 8 + 2 * t + 1] = *(const float4*)&x[base + 4];
      }
    }
    float4 bv[8];
#pragma unroll
    for (int kk = 0; kk < 2; ++kk) {
#pragma unroll
      for (int it = 0; it < 2; ++it) {
        const int k0 = it * 64 + bk * 2;             // local k (even), 0..126
        const size_t base = (size_t)((kk * 2 + z) * 128 + k0) * NC + c0 + bc;
        bv[kk * 4 + 2 * it]     = *(const float4*)&T[base];      // row k0
        bv[kk * 4 + 2 * it + 1] = *(const float4*)&T[base + NC]; // row k0+1
      }
    }

    // ======== write phase: convert + LDS ========
#pragma unroll
    for (int kk = 0; kk < 2; ++kk) {
#pragma unroll
      for (int t = 0; t < 4; ++t) {
        const int u = t * 256 + tid;
        const int row = u >> 4, seg = u & 15;
        uint4 p;
        p.x = f2bf(av[kk * 8 + 2 * t].x) | (f2bf(av[kk * 8 + 2 * t].y) << 16);
        p.y = f2bf(av[kk * 8 + 2 * t].z) | (f2bf(av[kk * 8 + 2 * t].w) << 16);
        p.z = f2bf(av[kk * 8 + 2 * t + 1].x) | (f2bf(av[kk * 8 + 2 * t + 1].y) << 16);
        p.w = f2bf(av[kk * 8 + 2 * t + 1].z) | (f2bf(av[kk * 8 + 2 * t + 1].w) << 16);
        *(uint4*)&Xs[kk * 64 * 136 + row * 136 + seg * 8] = p;
      }
      unsigned* Tw = (unsigned*)(Ts + kk * 32 * 136);   // dword view, row stride 68
#pragma unroll
      for (int it = 0; it < 2; ++it) {
        const float* lo = &bv[kk * 4 + 2 * it].x;
        const float* hi = &bv[kk * 4 + 2 * it + 1].x;
#pragma unroll
        for (int q = 0; q < 4; ++q) {
          const unsigned val = f2bf(lo[q]) | (f2bf(hi[q]) << 16);
          Tw[(bc + q) * 68 + it * 32 + bk] = val;      // Ts[kk][c][k0..k0+1]
        }
      }
    }

    __syncthreads();

    // ---- MFMA: 8 steps of K=16 on this wave's K-half ----
#pragma unroll
    for (int s = 0; s < 8; ++s) {
      const bf16x8 af = *(const bf16x8*)&Xs[kh * 64 * 136 + arow * 136 + s * 16 + half * 8];
      const bf16x8 bf = *(const bf16x8*)&Ts[kh * 32 * 136 + l31 * 136 + s * 16 + half * 8];
      acc = __builtin_amdgcn_mfma_f32_32x32x16_bf16(af, bf, acc, 0, 0, 0);
    }
    __syncthreads();
  }

  // ---- epilogue: partials -> Cs[kh], sync, sum + emit ----
#pragma unroll
  for (int reg = 0; reg < 16; ++reg) {
    const int row = (reg & 3) + 8 * (reg >> 2) + 4 * half;
    Cs[kh * 64 * 36 + (wr * 32 + row) * 36 + l31] = acc[reg];
  }
  __syncthreads();

  {
    const int jl = tid >> 6;                // local j 0..3
    const int b  = tid & 63;                // local b
    const float4 p0 = *(const float4*)&Cs[b * 36 + jl * 8];
    const float4 p1 = *(const float4*)&Cs[b * 36 + jl * 8 + 4];
    const float4 q0 = *(const float4*)&Cs[64 * 36 + b * 36 + jl * 8];
    const float4 q1 = *(const float4*)&Cs[64 * 36 + b * 36 + jl * 8 + 4];
    const float4 m0 = float4{p0.x + q0.x, p0.y + q0.y, p0.z + q0.z, p0.w + q0.w};
    const float4 m1 = float4{p1.x + q1.x, p1.y + q1.y, p1.z + q1.z, p1.w + q1.w};
    const int j_g = blockIdx.y * 4 + jl;
    const int idx = j_g * NB + b0 + b;
    ((float4*)Mp)[idx * 2]     = m0;
    ((float4*)Mp)[idx * 2 + 1] = m1;
    float s = m0.x * m0.x;
    s = fmaf(m0.y, m0.y, s); s = fmaf(m0.z, m0.z, s); s = fmaf(m0.w, m0.w, s);
    s = fmaf(m1.x, m1.x, s); s = fmaf(m1.y, m1.y, s); s = fmaf(m1.z, m1.z, s);
    s = fmaf(m1.w, m1.w, s);
    na[idx] = s;
    uint4 pk;
    pk.x = f2bf(m0.x) | (f2bf(m0.y) << 16);
    pk.y = f2bf(m0.z) | (f2bf(m0.w) << 16);
    pk.z = f2bf(m1.x) | (f2bf(m1.y) << 16);
    pk.w = f2bf(m1.z) | (f2bf(m1.w) << 16);
    Mb[idx] = pk;
  }
}

// ---------------------------------------------------------------------------
// Kernel 2: pairwise — byte-identical to the PROVEN 73.7us version (bh=2).
// (R6 barrier-free: +7.5us; R7 bh=4 split: +1.5us — both reverted.)
// ---------------------------------------------------------------------------
__global__ __launch_bounds__(256) void pairwise_kernel(const uint4* __restrict__ Mb,
                                                       const float* __restrict__ na,
                                                       const float* __restrict__ Mp,
                                                       float* __restrict__ out) {
  const int j    = blockIdx.x;
  const int ag   = blockIdx.y;
  const int bh   = blockIdx.z;
  const int tid  = threadIdx.x;
  const int lane = tid & 63;
  const int w    = tid >> 6;
  const int col  = lane & 31;
  const int h    = lane >> 5;
  const int jb   = j * NB;

  __shared__ uint4 Mb_s[513];    // [512] = zeros for K-pad lanes
  __shared__ float nb_s[512];
  __shared__ float na_s[128];

  const int bbeg = bh * 512;
  Mb_s[tid]       = Mb[jb + bbeg + tid];
  Mb_s[tid + 256] = Mb[jb + bbeg + tid + 256];
  nb_s[tid]       = na[jb + bbeg + tid];
  nb_s[tid + 256] = na[jb + bbeg + tid + 256];
  if (tid == 0) Mb_s[512] = uint4{0u, 0u, 0u, 0u};

  const int a0 = ag * 128 + w * 32;
  if (lane < 32) na_s[w * 32 + lane] = na[jb + a0 + lane];

  uint4 araw = uint4{0u, 0u, 0u, 0u};
  if (lane < 32) araw = Mb[jb + a0 + lane];
  const bf16x8 af = __builtin_bit_cast(bf16x8, araw);

  __syncthreads();

  float c995[16];
#pragma unroll
  for (int reg = 0; reg < 16; ++reg) {
    const int row = (reg & 3) + 8 * (reg >> 2) + 4 * h;
    c995[reg] = 0.995f * na_s[w * 32 + row];
  }

  const floatx16 zero = {};

#pragma unroll 2
  for (int bt = 0; bt < 16; ++bt) {
    const int bidx = bt * 32 + col;
    const uint4 braw = Mb_s[lane < 32 ? bidx : 512];
    const bf16x8 bf = __builtin_bit_cast(bf16x8, braw);
    const floatx16 P = __builtin_amdgcn_mfma_f32_32x32x16_bf16(af, bf, zero, 0, 0, 0);
    const float nb_l = nb_s[bidx];
    const float rhs = 100.0f - 0.995f * nb_l;

    float t = fmaf(-2.0f, P[0], c995[0]);
#pragma unroll
    for (int reg = 1; reg < 16; ++reg)
      t = fminf(t, fmaf(-2.0f, P[reg], c995[reg]));

    if (__any(t < rhs)) {   // rare: ~diagonal tiles only
#pragma unroll
      for (int reg = 0; reg < 16; ++reg) {
        if (fmaf(-2.0f, P[reg], c995[reg]) < rhs) {
          const int row = (reg & 3) + 8 * (reg >> 2) + 4 * h;
          const int a = a0 + row;
          const int b = bbeg + bt * 32 + col;
          float corr;
          if (a == b) {
            corr = 1.0f - EXPN10;
          } else {
            const float4 av0 = ((const float4*)Mp)[(jb + a) * 2];
            const float4 av1 = ((const float4*)Mp)[(jb + a) * 2 + 1];
            const float4 bv0 = ((const float4*)Mp)[(jb + b) * 2];
            const float4 bv1 = ((const float4*)Mp)[(jb + b) * 2 + 1];
            float d = av0.x - bv0.x; float sq = d * d;
            d = av0.y - bv0.y; sq = fmaf(d, d, sq);
            d = av0.z - bv0.z; sq = fmaf(d, d, sq);
            d = av0.w - bv0.w; sq = fmaf(d, d, sq);
            d = av1.x - bv1.x; sq = fmaf(d, d, sq);
            d = av1.y - bv1.y; sq = fmaf(d, d, sq);
            d = av1.z - bv1.z; sq = fmaf(d, d, sq);
            d = av1.w - bv1.w; sq = fmaf(d, d, sq);
            const float nrm = sqrtf(sq);
            corr = (nrm < 10.0f) ? (__expf(-nrm) - EXPN10) : 0.0f;
          }
          if (corr != 0.0f) atomicAdd(&out[a * OUTC + NIN + j], corr);
        }
      }
    }
  }
}

// ---------------------------------------------------------------------------
extern "C" void kernel_launch(void* const* d_in, const int* in_sizes, int n_in,
                              void* d_out, int out_size, void* d_ws, size_t ws_size,
                              hipStream_t stream) {
  const float* x = (const float*)d_in[0];
  const float* T = (const float*)d_in[1];
  float* out = (float*)d_out;

  // workspace layout (3.25 MB)
  float* Mp  = (float*)d_ws;                         // [64][1024][8] fp32   2 MB
  float* na  = Mp + (size_t)NJ * NB * NK;            // [64][1024]         256 KB
  uint4* Mb  = (uint4*)(na + (size_t)NJ * NB);       // [64][1024] bf16x8    1 MB

  gemm_fused<<<dim3(16, 16), 256, 0, stream>>>(x, T, Mp, Mb, na, out);
  pairwise_kernel<<<dim3(NJ, 8, 2), 256, 0, stream>>>(Mb, na, Mp, out);
}